// Round 19
// baseline (336.182 us; speedup 1.0000x reference)
//
#include <hip/hip_runtime.h>

// ---------------------------------------------------------------------------
// CausalSelfAttention forward on MI355X (gfx950).
// B=4, T=2048, C=1024, H=16, hs=64.
// Pipeline: [fused prep: cvt x->bf16 + transpose W's, ONE launch] ->
//           QKV GEMM (r18: 128x128, hoisted offsets, linear epilogue) ->
//           flash attention (GLOBAL-direct K/V, barrier-free, fixed-shift
//           softmax) -> proj GEMM (r18).
// r18 banked at 157.8us (QKV 68 / attn ~47 / proj ~22 / prep ~13).
// This round: (1) attn drops K/V LDS staging (K+V L2/L3-resident; no
// barriers, no vmcnt, LDS 40K->8K, residency ~3->~5 blocks/CU); (2) prep
// fused into one kernel (2 fewer launch gaps).
// Workspace layout (bytes):
//   xb    @ 0         : 8192x1024 bf16           (16,777,216)
//   WaT   @ 16777216  : 3072x1024 bf16           ( 6,291,456)
//   WpT   @ 23068672  : 1024x1024 bf16           ( 2,097,152)
//   Q     @ 25165824  : [64][2048][64] bf16      (pre-scaled by log2e/8)
//   K     @ 41943040  : [64][2048][64] bf16
//   Vt    @ 58720256  : [64][64][2048] bf16      (V transposed per head)
//   Y     @ 75497472  : 8192x1024 bf16
// ---------------------------------------------------------------------------

typedef __bf16 bf16_t;
typedef __bf16 bf16x8 __attribute__((ext_vector_type(8)));
typedef __bf16 bf16x4 __attribute__((ext_vector_type(4)));
typedef float  f32x4  __attribute__((ext_vector_type(4)));

#define MFMA16(a, b, c) __builtin_amdgcn_mfma_f32_16x16x32_bf16((a), (b), (c), 0, 0, 0)

static __device__ __forceinline__ void gld_lds16(const bf16_t* g, void* l) {
  __builtin_amdgcn_global_load_lds(
      (const __attribute__((address_space(1))) void*)(const void*)g,
      (__attribute__((address_space(3))) void*)l, 16, 0, 0);
}

static __device__ __forceinline__ bf16x8 ldv8(const void* p) {
  return *reinterpret_cast<const bf16x8*>(p);
}

static __device__ __forceinline__ float exp2_hw(float x) {
  float r;
  asm("v_exp_f32 %0, %1" : "=v"(r) : "v"(x));
  return r;
}

// --------------------------------------------------------- fused prep ----
// One launch, sectioned by blockIdx.x:
//   [0, 8192)        : x f32 -> xb bf16 (float4 vectorized)
//   [8192, 11264)    : W_attn [1024][3072] -> WaT [3072][1024] bf16
//   [11264, 12288)   : W_proj [1024][1024] -> WpT [1024][1024] bf16
__global__ __launch_bounds__(256) void prep_fused(
    const float* __restrict__ x, bf16_t* __restrict__ xb,
    const float* __restrict__ Wa, bf16_t* __restrict__ WaT,
    const float* __restrict__ Wp, bf16_t* __restrict__ WpT) {
  __shared__ float tile[32][33];
  const int bid = blockIdx.x;
  const int tid = threadIdx.x;

  if (bid < 8192) {                       // cvt x -> bf16
    const int i = bid * 256 + tid;        // 2,097,152 float4 total
    float4 v = reinterpret_cast<const float4*>(x)[i];
    bf16x4 o;
    o[0] = (bf16_t)v.x; o[1] = (bf16_t)v.y; o[2] = (bf16_t)v.z; o[3] = (bf16_t)v.w;
    reinterpret_cast<bf16x4*>(xb)[i] = o;
    return;
  }
  const bool isA = bid < 11264;
  const int tb = isA ? (bid - 8192) : (bid - 11264);
  const int Nd = isA ? 3072 : 1024;
  const int nbx = isA ? 96 : 32;
  const float* in = isA ? Wa : Wp;
  bf16_t* out = isA ? WaT : WpT;
  const int n0 = (tb % nbx) * 32, k0 = (tb / nbx) * 32;
  const int tx = tid & 31, ty = tid >> 5;
#pragma unroll
  for (int i = 0; i < 4; ++i)
    tile[ty + i * 8][tx] = in[(size_t)(k0 + ty + i * 8) * Nd + (n0 + tx)];
  __syncthreads();
#pragma unroll
  for (int i = 0; i < 4; ++i)
    out[(size_t)(n0 + ty + i * 8) * 1024 + (k0 + tx)] = (bf16_t)tile[tx][ty + i * 8];
}

// ---------------------------------------------------------------- GEMM ----
// (r18-verified, unchanged: 128x128, BK=64, 4 waves, gld_lds + source-side
// XOR swizzle, XCD-chunked M-fastest, hoisted LDS offsets, KD templated,
// block-uniform linear epilogue.)
template <int MODE, int KD>
__global__ __launch_bounds__(256) void gemm_bf16(
    const bf16_t* __restrict__ A, const bf16_t* __restrict__ Bt,
    const float* __restrict__ bias, int M, int N,
    bf16_t* __restrict__ Qo, bf16_t* __restrict__ Ko, bf16_t* __restrict__ Vt,
    float* __restrict__ Co) {
  __shared__ alignas(16) char lds[32768];

  const int tid = threadIdx.x;
  const int wave = tid >> 6, lane = tid & 63;
  const int wm = wave >> 1, wn = wave & 1;
  const int l16 = lane & 15, kb = lane >> 4;
  const int r7 = l16 & 7;

  const int nbx = gridDim.x;
  const int lb = blockIdx.y * nbx + blockIdx.x;
  const int c = lb & 7;
  const int ii = lb >> 3;
  const int rPer = gridDim.y >> 3;
  const int tmt = c * rPer + (ii % rPer);
  const int tnt = ii / rPer;
  const int tm0 = tmt * 128, tn0 = tnt * 128;

  const int srow = wave * 8 + (lane >> 3);
  const int sp = lane & 7;

  unsigned aOff[2][4], bOff[2][4];
#pragma unroll
  for (int kc = 0; kc < 2; ++kc)
#pragma unroll
    for (int i = 0; i < 4; ++i) {
      const int rowA = wm * 64 + i * 16 + l16;
      const int rowB = wn * 64 + i * 16 + l16;
      const int slot = (kc * 4 + kb) ^ r7;
      aOff[kc][i] = rowA * 128 + slot * 16;
      bOff[kc][i] = 16384 + rowB * 128 + slot * 16;
    }

  const bf16_t* aR = A + (size_t)(tm0 + srow) * KD + sp * 8;
  const bf16_t* bR = Bt + (size_t)(tn0 + srow) * KD + sp * 8;
  const int schx = ((sp ^ (srow & 7)) - sp) * 8;

  f32x4 acc[4][4] = {};

  for (int k0 = 0; k0 < KD; k0 += 64) {
    __syncthreads();
#pragma unroll
    for (int inst = 0; inst < 4; ++inst) {
      gld_lds16(aR + (size_t)(inst * 32) * KD + k0 + schx,
                &lds[inst * 4096 + wave * 1024]);
      gld_lds16(bR + (size_t)(inst * 32) * KD + k0 + schx,
                &lds[16384 + inst * 4096 + wave * 1024]);
    }
    __syncthreads();
#pragma unroll
    for (int kc = 0; kc < 2; ++kc) {
      bf16x8 af[4], bfr[4];
#pragma unroll
      for (int mi = 0; mi < 4; ++mi) af[mi] = ldv8(&lds[aOff[kc][mi]]);
#pragma unroll
      for (int ni = 0; ni < 4; ++ni) bfr[ni] = ldv8(&lds[bOff[kc][ni]]);
#pragma unroll
      for (int mi = 0; mi < 4; ++mi)
#pragma unroll
        for (int ni = 0; ni < 4; ++ni)
          acc[mi][ni] = MFMA16(af[mi], bfr[ni], acc[mi][ni]);
    }
  }

  if constexpr (MODE == 0) {
    const int which = tn0 >> 10;
    const int bb = tm0 >> 11;
    const int t0 = (tm0 & 2047) + wm * 64 + kb * 4;
    const int hn0 = (tn0 & 1023) + wn * 64;
    const int hh = bb * 16 + (hn0 >> 6);

    if (which == 2) {
#pragma unroll
      for (int ni = 0; ni < 4; ++ni) {
        const int d = ni * 16 + l16;
        const float bv = bias[2048 + hn0 + d];
        bf16_t* p = Vt + ((size_t)hh * 64 + d) * 2048;
#pragma unroll
        for (int mi = 0; mi < 4; ++mi) {
          bf16x4 v4;
#pragma unroll
          for (int j = 0; j < 4; ++j) v4[j] = (bf16_t)(acc[mi][ni][j] + bv);
          *reinterpret_cast<bf16x4*>(&p[t0 + mi * 16]) = v4;
        }
      }
    } else {
      bf16_t* dst = which ? Ko : Qo;
      const float scl = which ? 1.0f : 0.18033688011112042f;  // log2e/8 on Q
#pragma unroll
      for (int ni = 0; ni < 4; ++ni) {
        const int d = ni * 16 + l16;
        const float bv = bias[which * 1024 + hn0 + d];
        bf16_t* p = dst + (size_t)hh * 131072 + d;
#pragma unroll
        for (int mi = 0; mi < 4; ++mi)
#pragma unroll
          for (int j = 0; j < 4; ++j)
            p[(size_t)(t0 + mi * 16 + j) * 64] = (bf16_t)((acc[mi][ni][j] + bv) * scl);
      }
    }
  } else {
#pragma unroll
    for (int ni = 0; ni < 4; ++ni) {
      const int n = tn0 + wn * 64 + ni * 16 + l16;
      const float bv = bias[n];
#pragma unroll
      for (int mi = 0; mi < 4; ++mi) {
#pragma unroll
        for (int j = 0; j < 4; ++j) {
          const int m = tm0 + wm * 64 + mi * 16 + kb * 4 + j;
          Co[(size_t)m * N + n] = acc[mi][ni][j] + bv;
        }
      }
    }
  }
}

// ----------------------------------------------------------- attention ----
// BARRIER-FREE: K/V fragments read DIRECTLY from global (per-XCD K+V
// working set spans L2+L3 — both latency-hideable with the higher
// residency this buys; guide mistake #7 / m169 precedent). LDS = P only
// (8KB, wave-private roundtrip, lgkm-ordered). No __syncthreads, no
// vmcnt drains anywhere -> the block's 4 waves fully decouple.
// Structure otherwise r18: single q-tile/block (64 rows, 4 waves x 16),
// 2048 blocks LPT, swapped-QK, FIXED-SHIFT softmax (C-init -16, exact
// shift invariance), partial l_r reduced in epilogue, hoisted addresses.
__global__ __launch_bounds__(256) void attn_fwd(const bf16_t* __restrict__ Qg,
                                                const bf16_t* __restrict__ Kg,
                                                const bf16_t* __restrict__ Vtg,
                                                bf16_t* __restrict__ Yg) {
  __shared__ alignas(16) char lds[8192];   // P: 4 waves x 2KB

  const int tid = threadIdx.x;
  const int wave = tid >> 6, lane = tid & 63;
  const int l16 = lane & 15, kb = lane >> 4;
  const int l8 = l16 & 7;
  const float NEG_INF = -__builtin_inff();

  const int n = blockIdx.x;                    // 2048 blocks
  const int bh = (n & 7) * 8 + ((n >> 3) & 7); // 8 heads per XCD
  const int qt = 31 - (n >> 6);                // longest-first (LPT)
  const size_t base = (size_t)bh * (2048 * 64);
  const int b = bh >> 4, h = bh & 15;

  const int q0 = qt * 64 + wave * 16;
  const int q = q0 + l16;                      // this lane's q-row
  const int trips = qt + 1;

  const bf16x8 qf0 = ldv8(Qg + base + (size_t)q * 64 + kb * 8);
  const bf16x8 qf1 = ldv8(Qg + base + (size_t)q * 64 + 32 + kb * 8);

  f32x4 o[4] = {};
  float l_r = 0.f;

  // hoisted P-roundtrip offsets (loop-invariant)
  char* Pw = lds + wave * 2048;
  unsigned pwOff[4];
#pragma unroll
  for (int i = 0; i < 4; ++i) {
    const int phys = (i * 2 + (kb >> 1)) ^ l8;
    pwOff[i] = l16 * 128 + phys * 16 + (kb & 1) * 8;
  }
  const unsigned pr0 = l16 * 128 + ((kb ^ l8) * 16);
  const unsigned pr1 = l16 * 128 + (((4 + kb) ^ l8) * 16);

  // per-lane global K/V bases (loop-invariant)
  const bf16_t* Kl = Kg + base + (size_t)l16 * 64 + kb * 8;      // +(kv0+i*16)*64 +kc*32
  const bf16_t* Vl = Vtg + base + (size_t)l16 * 2048 + kb * 8;   // +i*16*2048 +kv0 +kc*32

  for (int t = 0; t < trips; ++t) {
    const int kv0 = t * 64;

    bf16x8 kf[8];
#pragma unroll
    for (int i = 0; i < 4; ++i) {
      const bf16_t* kr = Kl + (size_t)(kv0 + i * 16) * 64;
      kf[i * 2 + 0] = ldv8(kr);
      kf[i * 2 + 1] = ldv8(kr + 32);
    }

    // fixed-shift softmax: C-init = -16 (shift folded into the MFMA)
    f32x4 s[4];
#pragma unroll
    for (int i = 0; i < 4; ++i) s[i] = f32x4{-16.f, -16.f, -16.f, -16.f};
    __builtin_amdgcn_s_setprio(1);
#pragma unroll
    for (int i = 0; i < 4; ++i) {
      s[i] = MFMA16(kf[i * 2 + 0], qf0, s[i]);
      s[i] = MFMA16(kf[i * 2 + 1], qf1, s[i]);
    }
    __builtin_amdgcn_s_setprio(0);

    bf16x8 vf[8];
#pragma unroll
    for (int i = 0; i < 4; ++i) {
      const bf16_t* vr = Vl + (size_t)(i * 16) * 2048 + kv0;
      vf[i * 2 + 0] = ldv8(vr);
      vf[i * 2 + 1] = ldv8(vr + 32);
    }

    // diagonal tile: causal mask (wave-uniform branch); exp2(-inf) = 0
    if (t == qt) {
#pragma unroll
      for (int i = 0; i < 4; ++i)
#pragma unroll
        for (int j = 0; j < 4; ++j)
          if (kv0 + i * 16 + kb * 4 + j > q) s[i][j] = NEG_INF;
    }

    float ss = 0.f;
    bf16x4 pw[4];
#pragma unroll
    for (int i = 0; i < 4; ++i)
#pragma unroll
      for (int j = 0; j < 4; ++j) {
        const float p = exp2_hw(s[i][j]);
        ss += p;
        pw[i][j] = (bf16_t)p;
      }
    l_r += ss;                                  // partial; reduced in epilogue

    // P^T roundtrip, wave-private (lgkm-ordered; no barrier needed)
#pragma unroll
    for (int i = 0; i < 4; ++i)
      *reinterpret_cast<bf16x4*>(Pw + pwOff[i]) = pw[i];
    const bf16x8 pb0 = ldv8(Pw + pr0);
    const bf16x8 pb1 = ldv8(Pw + pr1);

    __builtin_amdgcn_s_setprio(1);
#pragma unroll
    for (int i = 0; i < 4; ++i) {
      o[i] = MFMA16(vf[i * 2 + 0], pb0, o[i]);
      o[i] = MFMA16(vf[i * 2 + 1], pb1, o[i]);
    }
    __builtin_amdgcn_s_setprio(0);
  }

  float lt = l_r + __shfl_xor(l_r, 16);
  lt += __shfl_xor(lt, 32);
  const float inv = 1.0f / lt;
  bf16_t* yrow = Yg + ((size_t)(b * 2048 + q)) * 1024 + h * 64;
#pragma unroll
  for (int i = 0; i < 4; ++i) {
    bf16x4 yv;
    yv[0] = (bf16_t)(o[i][0] * inv);
    yv[1] = (bf16_t)(o[i][1] * inv);
    yv[2] = (bf16_t)(o[i][2] * inv);
    yv[3] = (bf16_t)(o[i][3] * inv);
    *reinterpret_cast<bf16x4*>(yrow + i * 16 + kb * 4) = yv;
  }
}

// --------------------------------------------------------------- launch ---
extern "C" void kernel_launch(void* const* d_in, const int* in_sizes, int n_in,
                              void* d_out, int out_size, void* d_ws, size_t ws_size,
                              hipStream_t stream) {
  const float* x = (const float*)d_in[0];
  const float* W_attn = (const float*)d_in[1];
  const float* b_attn = (const float*)d_in[2];
  const float* W_proj = (const float*)d_in[3];
  const float* b_proj = (const float*)d_in[4];
  float* out = (float*)d_out;

  char* ws = (char*)d_ws;
  bf16_t* xb  = (bf16_t*)(ws + 0);
  bf16_t* WaT = (bf16_t*)(ws + 16777216);
  bf16_t* WpT = (bf16_t*)(ws + 23068672);
  bf16_t* Qb  = (bf16_t*)(ws + 25165824);
  bf16_t* Kb  = (bf16_t*)(ws + 41943040);
  bf16_t* Vt  = (bf16_t*)(ws + 58720256);
  bf16_t* Yb  = (bf16_t*)(ws + 75497472);

  // fused prep: cvt (8192 blocks) + W_attn transpose (3072) + W_proj (1024)
  prep_fused<<<12288, 256, 0, stream>>>(x, xb, W_attn, WaT, W_proj, WpT);

  // qkv: M=8192, N=3072 -> grid 24x64 = 1536 blocks
  gemm_bf16<0, 1024><<<dim3(24, 64), 256, 0, stream>>>(xb, WaT, b_attn, 8192, 3072,
                                                       Qb, Kb, Vt, nullptr);

  attn_fwd<<<2048, 256, 0, stream>>>(Qb, Kb, Vt, Yb);

  // proj: M=8192, N=1024 -> grid 8x64 = 512 blocks
  gemm_bf16<1, 1024><<<dim3(8, 64), 256, 0, stream>>>(Yb, WpT, b_proj, 8192, 1024,
                                                      nullptr, nullptr, nullptr, out);
}

// Round 20
// 155.860 us; speedup vs baseline: 2.1570x; 2.1570x over previous
//
#include <hip/hip_runtime.h>

// ---------------------------------------------------------------------------
// CausalSelfAttention forward on MI355X (gfx950).
// B=4, T=2048, C=1024, H=16, hs=64.
// Pipeline: [fused prep] -> QKV GEMM (r18) -> flash attention (r18-verified:
//           staged dbuf K/V + fixed-shift softmax) -> proj GEMM (r18).
// r19 post-mortem: global-direct K/V removed the prefetch engine (staging
// issued tile t+1's loads under tile t's compute); with per-XCD K+V ~8MB >
// L2, exposed L3/HBM latency collapsed attn 47->253us. REVERTED to the r18
// attention verbatim; fused prep kept (orthogonal).
// Workspace layout (bytes):
//   xb    @ 0         : 8192x1024 bf16           (16,777,216)
//   WaT   @ 16777216  : 3072x1024 bf16           ( 6,291,456)
//   WpT   @ 23068672  : 1024x1024 bf16           ( 2,097,152)
//   Q     @ 25165824  : [64][2048][64] bf16      (pre-scaled by log2e/8)
//   K     @ 41943040  : [64][2048][64] bf16
//   Vt    @ 58720256  : [64][64][2048] bf16      (V transposed per head)
//   Y     @ 75497472  : 8192x1024 bf16
// ---------------------------------------------------------------------------

typedef __bf16 bf16_t;
typedef __bf16 bf16x8 __attribute__((ext_vector_type(8)));
typedef __bf16 bf16x4 __attribute__((ext_vector_type(4)));
typedef float  f32x4  __attribute__((ext_vector_type(4)));

#define MFMA16(a, b, c) __builtin_amdgcn_mfma_f32_16x16x32_bf16((a), (b), (c), 0, 0, 0)

static __device__ __forceinline__ void gld_lds16(const bf16_t* g, void* l) {
  __builtin_amdgcn_global_load_lds(
      (const __attribute__((address_space(1))) void*)(const void*)g,
      (__attribute__((address_space(3))) void*)l, 16, 0, 0);
}

static __device__ __forceinline__ bf16x8 ldv8(const void* p) {
  return *reinterpret_cast<const bf16x8*>(p);
}

static __device__ __forceinline__ float exp2_hw(float x) {
  float r;
  asm("v_exp_f32 %0, %1" : "=v"(r) : "v"(x));
  return r;
}

// --------------------------------------------------------- fused prep ----
// One launch, sectioned by blockIdx.x:
//   [0, 8192)        : x f32 -> xb bf16 (float4 vectorized)
//   [8192, 11264)    : W_attn [1024][3072] -> WaT [3072][1024] bf16
//   [11264, 12288)   : W_proj [1024][1024] -> WpT [1024][1024] bf16
__global__ __launch_bounds__(256) void prep_fused(
    const float* __restrict__ x, bf16_t* __restrict__ xb,
    const float* __restrict__ Wa, bf16_t* __restrict__ WaT,
    const float* __restrict__ Wp, bf16_t* __restrict__ WpT) {
  __shared__ float tile[32][33];
  const int bid = blockIdx.x;
  const int tid = threadIdx.x;

  if (bid < 8192) {                       // cvt x -> bf16
    const int i = bid * 256 + tid;        // 2,097,152 float4 total
    float4 v = reinterpret_cast<const float4*>(x)[i];
    bf16x4 o;
    o[0] = (bf16_t)v.x; o[1] = (bf16_t)v.y; o[2] = (bf16_t)v.z; o[3] = (bf16_t)v.w;
    reinterpret_cast<bf16x4*>(xb)[i] = o;
    return;
  }
  const bool isA = bid < 11264;
  const int tb = isA ? (bid - 8192) : (bid - 11264);
  const int Nd = isA ? 3072 : 1024;
  const int nbx = isA ? 96 : 32;
  const float* in = isA ? Wa : Wp;
  bf16_t* out = isA ? WaT : WpT;
  const int n0 = (tb % nbx) * 32, k0 = (tb / nbx) * 32;
  const int tx = tid & 31, ty = tid >> 5;
#pragma unroll
  for (int i = 0; i < 4; ++i)
    tile[ty + i * 8][tx] = in[(size_t)(k0 + ty + i * 8) * Nd + (n0 + tx)];
  __syncthreads();
#pragma unroll
  for (int i = 0; i < 4; ++i)
    out[(size_t)(n0 + ty + i * 8) * 1024 + (k0 + tx)] = (bf16_t)tile[tx][ty + i * 8];
}

// ---------------------------------------------------------------- GEMM ----
// (r18-verified, unchanged: 128x128, BK=64, 4 waves, gld_lds + source-side
// XOR swizzle, XCD-chunked M-fastest, hoisted LDS offsets, KD templated,
// block-uniform linear epilogue.)
template <int MODE, int KD>
__global__ __launch_bounds__(256) void gemm_bf16(
    const bf16_t* __restrict__ A, const bf16_t* __restrict__ Bt,
    const float* __restrict__ bias, int M, int N,
    bf16_t* __restrict__ Qo, bf16_t* __restrict__ Ko, bf16_t* __restrict__ Vt,
    float* __restrict__ Co) {
  __shared__ alignas(16) char lds[32768];

  const int tid = threadIdx.x;
  const int wave = tid >> 6, lane = tid & 63;
  const int wm = wave >> 1, wn = wave & 1;
  const int l16 = lane & 15, kb = lane >> 4;
  const int r7 = l16 & 7;

  const int nbx = gridDim.x;
  const int lb = blockIdx.y * nbx + blockIdx.x;
  const int c = lb & 7;
  const int ii = lb >> 3;
  const int rPer = gridDim.y >> 3;
  const int tmt = c * rPer + (ii % rPer);
  const int tnt = ii / rPer;
  const int tm0 = tmt * 128, tn0 = tnt * 128;

  const int srow = wave * 8 + (lane >> 3);
  const int sp = lane & 7;

  unsigned aOff[2][4], bOff[2][4];
#pragma unroll
  for (int kc = 0; kc < 2; ++kc)
#pragma unroll
    for (int i = 0; i < 4; ++i) {
      const int rowA = wm * 64 + i * 16 + l16;
      const int rowB = wn * 64 + i * 16 + l16;
      const int slot = (kc * 4 + kb) ^ r7;
      aOff[kc][i] = rowA * 128 + slot * 16;
      bOff[kc][i] = 16384 + rowB * 128 + slot * 16;
    }

  const bf16_t* aR = A + (size_t)(tm0 + srow) * KD + sp * 8;
  const bf16_t* bR = Bt + (size_t)(tn0 + srow) * KD + sp * 8;
  const int schx = ((sp ^ (srow & 7)) - sp) * 8;

  f32x4 acc[4][4] = {};

  for (int k0 = 0; k0 < KD; k0 += 64) {
    __syncthreads();
#pragma unroll
    for (int inst = 0; inst < 4; ++inst) {
      gld_lds16(aR + (size_t)(inst * 32) * KD + k0 + schx,
                &lds[inst * 4096 + wave * 1024]);
      gld_lds16(bR + (size_t)(inst * 32) * KD + k0 + schx,
                &lds[16384 + inst * 4096 + wave * 1024]);
    }
    __syncthreads();
#pragma unroll
    for (int kc = 0; kc < 2; ++kc) {
      bf16x8 af[4], bfr[4];
#pragma unroll
      for (int mi = 0; mi < 4; ++mi) af[mi] = ldv8(&lds[aOff[kc][mi]]);
#pragma unroll
      for (int ni = 0; ni < 4; ++ni) bfr[ni] = ldv8(&lds[bOff[kc][ni]]);
#pragma unroll
      for (int mi = 0; mi < 4; ++mi)
#pragma unroll
        for (int ni = 0; ni < 4; ++ni)
          acc[mi][ni] = MFMA16(af[mi], bfr[ni], acc[mi][ni]);
    }
  }

  if constexpr (MODE == 0) {
    const int which = tn0 >> 10;
    const int bb = tm0 >> 11;
    const int t0 = (tm0 & 2047) + wm * 64 + kb * 4;
    const int hn0 = (tn0 & 1023) + wn * 64;
    const int hh = bb * 16 + (hn0 >> 6);

    if (which == 2) {
#pragma unroll
      for (int ni = 0; ni < 4; ++ni) {
        const int d = ni * 16 + l16;
        const float bv = bias[2048 + hn0 + d];
        bf16_t* p = Vt + ((size_t)hh * 64 + d) * 2048;
#pragma unroll
        for (int mi = 0; mi < 4; ++mi) {
          bf16x4 v4;
#pragma unroll
          for (int j = 0; j < 4; ++j) v4[j] = (bf16_t)(acc[mi][ni][j] + bv);
          *reinterpret_cast<bf16x4*>(&p[t0 + mi * 16]) = v4;
        }
      }
    } else {
      bf16_t* dst = which ? Ko : Qo;
      const float scl = which ? 1.0f : 0.18033688011112042f;  // log2e/8 on Q
#pragma unroll
      for (int ni = 0; ni < 4; ++ni) {
        const int d = ni * 16 + l16;
        const float bv = bias[which * 1024 + hn0 + d];
        bf16_t* p = dst + (size_t)hh * 131072 + d;
#pragma unroll
        for (int mi = 0; mi < 4; ++mi)
#pragma unroll
          for (int j = 0; j < 4; ++j)
            p[(size_t)(t0 + mi * 16 + j) * 64] = (bf16_t)((acc[mi][ni][j] + bv) * scl);
      }
    }
  } else {
#pragma unroll
    for (int ni = 0; ni < 4; ++ni) {
      const int n = tn0 + wn * 64 + ni * 16 + l16;
      const float bv = bias[n];
#pragma unroll
      for (int mi = 0; mi < 4; ++mi) {
#pragma unroll
        for (int j = 0; j < 4; ++j) {
          const int m = tm0 + wm * 64 + mi * 16 + kb * 4 + j;
          Co[(size_t)m * N + n] = acc[mi][ni][j] + bv;
        }
      }
    }
  }
}

// ----------------------------------------------------------- attention ----
// r18-VERIFIED (the 157.8us config), restored verbatim: single q-tile/block
// (64 rows, 4 waves x 16), 2048 blocks LPT, swapped-QK, staged dbuf K/V in
// LDS 40KB (the staging IS the prefetch engine: tile t+1's gld_lds issued
// under tile t's compute — r19's global-direct variant removed it and
// collapsed 47->253us), FIXED-SHIFT softmax (C-init -16), partial l_r,
// hoisted LDS read bases, one vmcnt(0)+barrier per iter.
__global__ __launch_bounds__(256) void attn_fwd(const bf16_t* __restrict__ Qg,
                                                const bf16_t* __restrict__ Kg,
                                                const bf16_t* __restrict__ Vtg,
                                                bf16_t* __restrict__ Yg) {
  __shared__ alignas(16) char lds[40960];  // K 2x8K @0, V 2x8K @16384, P 8K @32768

  const int tid = threadIdx.x;
  const int wave = tid >> 6, lane = tid & 63;
  const int l16 = lane & 15, kb = lane >> 4;
  const int l8 = l16 & 7;
  const float NEG_INF = -__builtin_inff();

  const int n = blockIdx.x;                    // 2048 blocks
  const int bh = (n & 7) * 8 + ((n >> 3) & 7); // 8 heads per XCD
  const int qt = 31 - (n >> 6);                // longest-first (LPT)
  const size_t base = (size_t)bh * (2048 * 64);
  const int b = bh >> 4, h = bh & 15;

  const int srow = tid >> 3;
  const int schunk = (tid & 7) ^ (srow & 7);
  const bf16_t* Ksrc = Kg + base + (size_t)srow * 64 + schunk * 8;
  const bf16_t* Vsrc = Vtg + base + (size_t)srow * 2048 + schunk * 8;

  auto stageK = [&](int buf, int kv0) {
    char* kd = lds + buf * 8192 + wave * 1024;
    const bf16_t* ks = Ksrc + (size_t)kv0 * 64;
    gld_lds16(ks, kd);
    gld_lds16(ks + 2048, kd + 4096);
  };
  auto stageV = [&](int buf, int kv0) {
    char* vd = lds + 16384 + buf * 8192 + wave * 1024;
    const bf16_t* vs = Vsrc + kv0;
    gld_lds16(vs, vd);
    gld_lds16(vs + 65536, vd + 4096);
  };

  const int q0 = qt * 64 + wave * 16;
  const int q = q0 + l16;                      // this lane's q-row
  const int trips = qt + 1;

  const bf16x8 qf0 = ldv8(Qg + base + (size_t)q * 64 + kb * 8);
  const bf16x8 qf1 = ldv8(Qg + base + (size_t)q * 64 + 32 + kb * 8);

  f32x4 o[4] = {};
  float l_r = 0.f;

  char* Pw = lds + 32768 + wave * 2048;
  const unsigned rb0 = l16 * 128 + ((kb ^ l8) * 16);        // kc=0 slot
  const unsigned rb1 = l16 * 128 + (((4 + kb) ^ l8) * 16);  // kc=1 slot

  stageK(0, 0);
  stageV(0, 0);
  asm volatile("s_waitcnt vmcnt(0)" ::: "memory");
  __builtin_amdgcn_s_barrier();
  __builtin_amdgcn_sched_barrier(0);

  int cur = 0;
  for (int t = 0; t < trips; ++t) {
    const int kv0 = t * 64;
    const bool more = (t + 1 < trips);
    if (more) {
      stageK(cur ^ 1, kv0 + 64);               // async, drains at iter end
      stageV(cur ^ 1, kv0 + 64);
    }

    const char* k0p = lds + cur * 8192 + rb0;
    const char* k1p = lds + cur * 8192 + rb1;
    const char* v0p = lds + 16384 + cur * 8192 + rb0;
    const char* v1p = lds + 16384 + cur * 8192 + rb1;

    bf16x8 kf[8];
#pragma unroll
    for (int i = 0; i < 4; ++i) {
      kf[i * 2 + 0] = ldv8(k0p + i * 2048);
      kf[i * 2 + 1] = ldv8(k1p + i * 2048);
    }

    // fixed-shift softmax: C-init = -16 (shift folded into the MFMA)
    f32x4 s[4];
#pragma unroll
    for (int i = 0; i < 4; ++i) s[i] = f32x4{-16.f, -16.f, -16.f, -16.f};
    __builtin_amdgcn_s_setprio(1);
#pragma unroll
    for (int i = 0; i < 4; ++i) {
      s[i] = MFMA16(kf[i * 2 + 0], qf0, s[i]);
      s[i] = MFMA16(kf[i * 2 + 1], qf1, s[i]);
    }
    __builtin_amdgcn_s_setprio(0);

    bf16x8 vf[8];
#pragma unroll
    for (int i = 0; i < 4; ++i) {
      vf[i * 2 + 0] = ldv8(v0p + i * 2048);
      vf[i * 2 + 1] = ldv8(v1p + i * 2048);
    }

    // diagonal tile: causal mask (wave-uniform branch); exp2(-inf) = 0
    if (t == qt) {
#pragma unroll
      for (int i = 0; i < 4; ++i)
#pragma unroll
        for (int j = 0; j < 4; ++j)
          if (kv0 + i * 16 + kb * 4 + j > q) s[i][j] = NEG_INF;
    }

    float ss = 0.f;
    bf16x4 pw[4];
#pragma unroll
    for (int i = 0; i < 4; ++i)
#pragma unroll
      for (int j = 0; j < 4; ++j) {
        const float p = exp2_hw(s[i][j]);
        ss += p;
        pw[i][j] = (bf16_t)p;
      }
    l_r += ss;                                  // partial; reduced in epilogue

    // P^T roundtrip, wave-private (16B-chunk XOR swizzle; verified r3-r18)
#pragma unroll
    for (int i = 0; i < 4; ++i) {
      const int phys = (i * 2 + (kb >> 1)) ^ l8;
      *reinterpret_cast<bf16x4*>(Pw + l16 * 128 + phys * 16 + (kb & 1) * 8) = pw[i];
    }
    const bf16x8 pb0 = ldv8(Pw + rb0);
    const bf16x8 pb1 = ldv8(Pw + rb1);

    __builtin_amdgcn_s_setprio(1);
#pragma unroll
    for (int i = 0; i < 4; ++i) {
      o[i] = MFMA16(vf[i * 2 + 0], pb0, o[i]);
      o[i] = MFMA16(vf[i * 2 + 1], pb1, o[i]);
    }
    __builtin_amdgcn_s_setprio(0);

    asm volatile("s_waitcnt vmcnt(0)" ::: "memory");
    __builtin_amdgcn_s_barrier();
    __builtin_amdgcn_sched_barrier(0);
    cur ^= 1;
  }

  float lt = l_r + __shfl_xor(l_r, 16);
  lt += __shfl_xor(lt, 32);
  const float inv = 1.0f / lt;
  bf16_t* yrow = Yg + ((size_t)(b * 2048 + q)) * 1024 + h * 64;
#pragma unroll
  for (int i = 0; i < 4; ++i) {
    bf16x4 yv;
    yv[0] = (bf16_t)(o[i][0] * inv);
    yv[1] = (bf16_t)(o[i][1] * inv);
    yv[2] = (bf16_t)(o[i][2] * inv);
    yv[3] = (bf16_t)(o[i][3] * inv);
    *reinterpret_cast<bf16x4*>(yrow + i * 16 + kb * 4) = yv;
  }
}

// --------------------------------------------------------------- launch ---
extern "C" void kernel_launch(void* const* d_in, const int* in_sizes, int n_in,
                              void* d_out, int out_size, void* d_ws, size_t ws_size,
                              hipStream_t stream) {
  const float* x = (const float*)d_in[0];
  const float* W_attn = (const float*)d_in[1];
  const float* b_attn = (const float*)d_in[2];
  const float* W_proj = (const float*)d_in[3];
  const float* b_proj = (const float*)d_in[4];
  float* out = (float*)d_out;

  char* ws = (char*)d_ws;
  bf16_t* xb  = (bf16_t*)(ws + 0);
  bf16_t* WaT = (bf16_t*)(ws + 16777216);
  bf16_t* WpT = (bf16_t*)(ws + 23068672);
  bf16_t* Qb  = (bf16_t*)(ws + 25165824);
  bf16_t* Kb  = (bf16_t*)(ws + 41943040);
  bf16_t* Vt  = (bf16_t*)(ws + 58720256);
  bf16_t* Yb  = (bf16_t*)(ws + 75497472);

  // fused prep: cvt (8192 blocks) + W_attn transpose (3072) + W_proj (1024)
  prep_fused<<<12288, 256, 0, stream>>>(x, xb, W_attn, WaT, W_proj, WpT);

  // qkv: M=8192, N=3072 -> grid 24x64 = 1536 blocks
  gemm_bf16<0, 1024><<<dim3(24, 64), 256, 0, stream>>>(xb, WaT, b_attn, 8192, 3072,
                                                       Qb, Kb, Vt, nullptr);

  attn_fwd<<<2048, 256, 0, stream>>>(Qb, Kb, Vt, Yb);

  // proj: M=8192, N=1024 -> grid 8x64 = 512 blocks
  gemm_bf16<1, 1024><<<dim3(8, 64), 256, 0, stream>>>(Yb, WpT, b_proj, 8192, 1024,
                                                      nullptr, nullptr, nullptr, out);
}

// Round 21
// 154.059 us; speedup vs baseline: 2.1822x; 1.0117x over previous
//
#include <hip/hip_runtime.h>

// ---------------------------------------------------------------------------
// CausalSelfAttention forward on MI355X (gfx950).
// B=4, T=2048, C=1024, H=16, hs=64.
// Pipeline: [fused prep] -> QKV GEMM (r18/r20) -> flash attention (8-wave
//           ADJACENT-PAIR blocks sharing staged K/V) -> proj GEMM (r18/r20).
// r20 banked 155.9us (QKV 67 / attn ~47 / proj ~22 / prep ~10).
// This round: attn only. Adjacent q-tile pair (2k, 2k+1) per 512-thread
// block: waves 0-3 own tile 2k, waves 4-7 own 2k+1, one shared kv sweep
// 0..2k+1. Group A idle ONLY at the final iteration (~3% waste) vs r5's
// (pp,31-pp) pairing which idled ~50%. Effect: block-iterations 528->272
// per bh (-48% staging/barrier/vmcnt events for identical compute), K/V
// FETCH halves, LDS 48KB -> 3 blocks x 8 waves = 24 waves/CU (vs 16).
// Per-wave inner body is byte-identical to r20 (staging prefetch engine
// kept — r19 showed it's load-bearing).
// Workspace layout (bytes):
//   xb    @ 0         : 8192x1024 bf16           (16,777,216)
//   WaT   @ 16777216  : 3072x1024 bf16           ( 6,291,456)
//   WpT   @ 23068672  : 1024x1024 bf16           ( 2,097,152)
//   Q     @ 25165824  : [64][2048][64] bf16      (pre-scaled by log2e/8)
//   K     @ 41943040  : [64][2048][64] bf16
//   Vt    @ 58720256  : [64][64][2048] bf16      (V transposed per head)
//   Y     @ 75497472  : 8192x1024 bf16
// ---------------------------------------------------------------------------

typedef __bf16 bf16_t;
typedef __bf16 bf16x8 __attribute__((ext_vector_type(8)));
typedef __bf16 bf16x4 __attribute__((ext_vector_type(4)));
typedef float  f32x4  __attribute__((ext_vector_type(4)));

#define MFMA16(a, b, c) __builtin_amdgcn_mfma_f32_16x16x32_bf16((a), (b), (c), 0, 0, 0)

static __device__ __forceinline__ void gld_lds16(const bf16_t* g, void* l) {
  __builtin_amdgcn_global_load_lds(
      (const __attribute__((address_space(1))) void*)(const void*)g,
      (__attribute__((address_space(3))) void*)l, 16, 0, 0);
}

static __device__ __forceinline__ bf16x8 ldv8(const void* p) {
  return *reinterpret_cast<const bf16x8*>(p);
}

static __device__ __forceinline__ float exp2_hw(float x) {
  float r;
  asm("v_exp_f32 %0, %1" : "=v"(r) : "v"(x));
  return r;
}

// --------------------------------------------------------- fused prep ----
// One launch, sectioned by blockIdx.x:
//   [0, 8192)        : x f32 -> xb bf16 (float4 vectorized)
//   [8192, 11264)    : W_attn [1024][3072] -> WaT [3072][1024] bf16
//   [11264, 12288)   : W_proj [1024][1024] -> WpT [1024][1024] bf16
__global__ __launch_bounds__(256) void prep_fused(
    const float* __restrict__ x, bf16_t* __restrict__ xb,
    const float* __restrict__ Wa, bf16_t* __restrict__ WaT,
    const float* __restrict__ Wp, bf16_t* __restrict__ WpT) {
  __shared__ float tile[32][33];
  const int bid = blockIdx.x;
  const int tid = threadIdx.x;

  if (bid < 8192) {                       // cvt x -> bf16
    const int i = bid * 256 + tid;        // 2,097,152 float4 total
    float4 v = reinterpret_cast<const float4*>(x)[i];
    bf16x4 o;
    o[0] = (bf16_t)v.x; o[1] = (bf16_t)v.y; o[2] = (bf16_t)v.z; o[3] = (bf16_t)v.w;
    reinterpret_cast<bf16x4*>(xb)[i] = o;
    return;
  }
  const bool isA = bid < 11264;
  const int tb = isA ? (bid - 8192) : (bid - 11264);
  const int Nd = isA ? 3072 : 1024;
  const int nbx = isA ? 96 : 32;
  const float* in = isA ? Wa : Wp;
  bf16_t* out = isA ? WaT : WpT;
  const int n0 = (tb % nbx) * 32, k0 = (tb / nbx) * 32;
  const int tx = tid & 31, ty = tid >> 5;
#pragma unroll
  for (int i = 0; i < 4; ++i)
    tile[ty + i * 8][tx] = in[(size_t)(k0 + ty + i * 8) * Nd + (n0 + tx)];
  __syncthreads();
#pragma unroll
  for (int i = 0; i < 4; ++i)
    out[(size_t)(n0 + ty + i * 8) * 1024 + (k0 + tx)] = (bf16_t)tile[tx][ty + i * 8];
}

// ---------------------------------------------------------------- GEMM ----
// (r18/r20-verified, unchanged: 128x128, BK=64, 4 waves, gld_lds + source-
// side XOR swizzle, XCD-chunked M-fastest, hoisted LDS offsets, KD
// templated, block-uniform linear epilogue.)
template <int MODE, int KD>
__global__ __launch_bounds__(256) void gemm_bf16(
    const bf16_t* __restrict__ A, const bf16_t* __restrict__ Bt,
    const float* __restrict__ bias, int M, int N,
    bf16_t* __restrict__ Qo, bf16_t* __restrict__ Ko, bf16_t* __restrict__ Vt,
    float* __restrict__ Co) {
  __shared__ alignas(16) char lds[32768];

  const int tid = threadIdx.x;
  const int wave = tid >> 6, lane = tid & 63;
  const int wm = wave >> 1, wn = wave & 1;
  const int l16 = lane & 15, kb = lane >> 4;
  const int r7 = l16 & 7;

  const int nbx = gridDim.x;
  const int lb = blockIdx.y * nbx + blockIdx.x;
  const int c = lb & 7;
  const int ii = lb >> 3;
  const int rPer = gridDim.y >> 3;
  const int tmt = c * rPer + (ii % rPer);
  const int tnt = ii / rPer;
  const int tm0 = tmt * 128, tn0 = tnt * 128;

  const int srow = wave * 8 + (lane >> 3);
  const int sp = lane & 7;

  unsigned aOff[2][4], bOff[2][4];
#pragma unroll
  for (int kc = 0; kc < 2; ++kc)
#pragma unroll
    for (int i = 0; i < 4; ++i) {
      const int rowA = wm * 64 + i * 16 + l16;
      const int rowB = wn * 64 + i * 16 + l16;
      const int slot = (kc * 4 + kb) ^ r7;
      aOff[kc][i] = rowA * 128 + slot * 16;
      bOff[kc][i] = 16384 + rowB * 128 + slot * 16;
    }

  const bf16_t* aR = A + (size_t)(tm0 + srow) * KD + sp * 8;
  const bf16_t* bR = Bt + (size_t)(tn0 + srow) * KD + sp * 8;
  const int schx = ((sp ^ (srow & 7)) - sp) * 8;

  f32x4 acc[4][4] = {};

  for (int k0 = 0; k0 < KD; k0 += 64) {
    __syncthreads();
#pragma unroll
    for (int inst = 0; inst < 4; ++inst) {
      gld_lds16(aR + (size_t)(inst * 32) * KD + k0 + schx,
                &lds[inst * 4096 + wave * 1024]);
      gld_lds16(bR + (size_t)(inst * 32) * KD + k0 + schx,
                &lds[16384 + inst * 4096 + wave * 1024]);
    }
    __syncthreads();
#pragma unroll
    for (int kc = 0; kc < 2; ++kc) {
      bf16x8 af[4], bfr[4];
#pragma unroll
      for (int mi = 0; mi < 4; ++mi) af[mi] = ldv8(&lds[aOff[kc][mi]]);
#pragma unroll
      for (int ni = 0; ni < 4; ++ni) bfr[ni] = ldv8(&lds[bOff[kc][ni]]);
#pragma unroll
      for (int mi = 0; mi < 4; ++mi)
#pragma unroll
        for (int ni = 0; ni < 4; ++ni)
          acc[mi][ni] = MFMA16(af[mi], bfr[ni], acc[mi][ni]);
    }
  }

  if constexpr (MODE == 0) {
    const int which = tn0 >> 10;
    const int bb = tm0 >> 11;
    const int t0 = (tm0 & 2047) + wm * 64 + kb * 4;
    const int hn0 = (tn0 & 1023) + wn * 64;
    const int hh = bb * 16 + (hn0 >> 6);

    if (which == 2) {
#pragma unroll
      for (int ni = 0; ni < 4; ++ni) {
        const int d = ni * 16 + l16;
        const float bv = bias[2048 + hn0 + d];
        bf16_t* p = Vt + ((size_t)hh * 64 + d) * 2048;
#pragma unroll
        for (int mi = 0; mi < 4; ++mi) {
          bf16x4 v4;
#pragma unroll
          for (int j = 0; j < 4; ++j) v4[j] = (bf16_t)(acc[mi][ni][j] + bv);
          *reinterpret_cast<bf16x4*>(&p[t0 + mi * 16]) = v4;
        }
      }
    } else {
      bf16_t* dst = which ? Ko : Qo;
      const float scl = which ? 1.0f : 0.18033688011112042f;  // log2e/8 on Q
#pragma unroll
      for (int ni = 0; ni < 4; ++ni) {
        const int d = ni * 16 + l16;
        const float bv = bias[which * 1024 + hn0 + d];
        bf16_t* p = dst + (size_t)hh * 131072 + d;
#pragma unroll
        for (int mi = 0; mi < 4; ++mi)
#pragma unroll
          for (int j = 0; j < 4; ++j)
            p[(size_t)(t0 + mi * 16 + j) * 64] = (bf16_t)((acc[mi][ni][j] + bv) * scl);
      }
    }
  } else {
#pragma unroll
    for (int ni = 0; ni < 4; ++ni) {
      const int n = tn0 + wn * 64 + ni * 16 + l16;
      const float bv = bias[n];
#pragma unroll
      for (int mi = 0; mi < 4; ++mi) {
#pragma unroll
        for (int j = 0; j < 4; ++j) {
          const int m = tm0 + wm * 64 + mi * 16 + kb * 4 + j;
          Co[(size_t)m * N + n] = acc[mi][ni][j] + bv;
        }
      }
    }
  }
}

// ----------------------------------------------------------- attention ----
// ADJACENT-PAIR 8-wave blocks: block owns q-tiles (2k, 2k+1); waves 0-3
// compute tile 2k, waves 4-7 tile 2k+1; ONE shared kv sweep 0..2k+1 with
// cooperative K/V staging across all 512 threads (1 gld_lds each for K and
// V per tile — same LDS layout as r20). Group A (tile 2k) is inactive only
// at t = trips-1 (wave-uniform guard). LDS 48KB: K dbuf 2x8K @0, V dbuf
// 2x8K @16384, P 8 waves x 2K @32768 -> 3 blocks/CU = 24 waves/CU.
// Per-wave body identical to r20: swapped-QK, FIXED-SHIFT softmax (C-init
// -16), partial l_r, hoisted LDS bases, dbuf staging (prefetch engine,
// r19 lesson), one vmcnt(0)+barrier per iter. LPT: longest pair first.
__global__ __launch_bounds__(512) void attn_fwd(const bf16_t* __restrict__ Qg,
                                                const bf16_t* __restrict__ Kg,
                                                const bf16_t* __restrict__ Vtg,
                                                bf16_t* __restrict__ Yg) {
  __shared__ alignas(16) char lds[49152];  // K 2x8K @0, V 2x8K @16384, P 16K @32768

  const int tid = threadIdx.x;
  const int wave = tid >> 6, lane = tid & 63;   // 8 waves
  const int wgrp = wave >> 2;                   // 0: tile 2k, 1: tile 2k+1
  const int wsub = wave & 3;
  const int l16 = lane & 15, kb = lane >> 4;
  const int l8 = l16 & 7;
  const float NEG_INF = -__builtin_inff();

  const int n = blockIdx.x;                    // 1024 blocks
  const int bh = (n & 7) * 8 + ((n >> 3) & 7); // 8 heads per XCD
  const int kp = 15 - (n >> 6);                // pair index, LPT (longest first)
  const int qtA = kp * 2;
  const int trips = qtA + 2;                   // sweep covers tile 2k+1
  const size_t base = (size_t)bh * (2048 * 64);
  const int b = bh >> 4, h = bh & 15;

  // cooperative staging: 512 threads x 16B = one full 64x64 bf16 tile
  const int srow = tid >> 3;                   // 0..63
  const int schunk = (tid & 7) ^ (srow & 7);   // source-side XOR swizzle
  const bf16_t* Ksrc = Kg + base + (size_t)srow * 64 + schunk * 8;
  const bf16_t* Vsrc = Vtg + base + (size_t)srow * 2048 + schunk * 8;

  auto stageK = [&](int buf, int kv0) {
    gld_lds16(Ksrc + (size_t)kv0 * 64, lds + buf * 8192 + wave * 1024);
  };
  auto stageV = [&](int buf, int kv0) {
    gld_lds16(Vsrc + kv0, lds + 16384 + buf * 8192 + wave * 1024);
  };

  const int qt = qtA + wgrp;                   // this wave's q-tile
  const int q0 = qt * 64 + wsub * 16;
  const int q = q0 + l16;                      // this lane's q-row

  const bf16x8 qf0 = ldv8(Qg + base + (size_t)q * 64 + kb * 8);
  const bf16x8 qf1 = ldv8(Qg + base + (size_t)q * 64 + 32 + kb * 8);

  f32x4 o[4] = {};
  float l_r = 0.f;

  char* Pw = lds + 32768 + wave * 2048;
  const unsigned rb0 = l16 * 128 + ((kb ^ l8) * 16);        // kc=0 slot
  const unsigned rb1 = l16 * 128 + (((4 + kb) ^ l8) * 16);  // kc=1 slot

  stageK(0, 0);
  stageV(0, 0);
  asm volatile("s_waitcnt vmcnt(0)" ::: "memory");
  __builtin_amdgcn_s_barrier();
  __builtin_amdgcn_sched_barrier(0);

  int cur = 0;
  for (int t = 0; t < trips; ++t) {
    const int kv0 = t * 64;
    const bool more = (t + 1 < trips);
    if (more) {
      stageK(cur ^ 1, kv0 + 64);               // async, drains at iter end
      stageV(cur ^ 1, kv0 + 64);
    }

    // group A inactive only on the final tile (t == qtA+1); wave-uniform
    if (wgrp || t <= qtA) {
      const char* k0p = lds + cur * 8192 + rb0;
      const char* k1p = lds + cur * 8192 + rb1;
      const char* v0p = lds + 16384 + cur * 8192 + rb0;
      const char* v1p = lds + 16384 + cur * 8192 + rb1;

      bf16x8 kf[8];
#pragma unroll
      for (int i = 0; i < 4; ++i) {
        kf[i * 2 + 0] = ldv8(k0p + i * 2048);
        kf[i * 2 + 1] = ldv8(k1p + i * 2048);
      }

      // fixed-shift softmax: C-init = -16 (shift folded into the MFMA)
      f32x4 s[4];
#pragma unroll
      for (int i = 0; i < 4; ++i) s[i] = f32x4{-16.f, -16.f, -16.f, -16.f};
      __builtin_amdgcn_s_setprio(1);
#pragma unroll
      for (int i = 0; i < 4; ++i) {
        s[i] = MFMA16(kf[i * 2 + 0], qf0, s[i]);
        s[i] = MFMA16(kf[i * 2 + 1], qf1, s[i]);
      }
      __builtin_amdgcn_s_setprio(0);

      bf16x8 vf[8];
#pragma unroll
      for (int i = 0; i < 4; ++i) {
        vf[i * 2 + 0] = ldv8(v0p + i * 2048);
        vf[i * 2 + 1] = ldv8(v1p + i * 2048);
      }

      // diagonal tile: causal mask (wave-uniform); exp2(-inf) = 0
      if (t == qt) {
#pragma unroll
        for (int i = 0; i < 4; ++i)
#pragma unroll
          for (int j = 0; j < 4; ++j)
            if (kv0 + i * 16 + kb * 4 + j > q) s[i][j] = NEG_INF;
      }

      float ss = 0.f;
      bf16x4 pw[4];
#pragma unroll
      for (int i = 0; i < 4; ++i)
#pragma unroll
        for (int j = 0; j < 4; ++j) {
          const float p = exp2_hw(s[i][j]);
          ss += p;
          pw[i][j] = (bf16_t)p;
        }
      l_r += ss;                                // partial; reduced in epilogue

      // P^T roundtrip, wave-private (16B-chunk XOR swizzle; verified r3-r20)
#pragma unroll
      for (int i = 0; i < 4; ++i) {
        const int phys = (i * 2 + (kb >> 1)) ^ l8;
        *reinterpret_cast<bf16x4*>(Pw + l16 * 128 + phys * 16 + (kb & 1) * 8) = pw[i];
      }
      const bf16x8 pb0 = ldv8(Pw + rb0);
      const bf16x8 pb1 = ldv8(Pw + rb1);

      __builtin_amdgcn_s_setprio(1);
#pragma unroll
      for (int i = 0; i < 4; ++i) {
        o[i] = MFMA16(vf[i * 2 + 0], pb0, o[i]);
        o[i] = MFMA16(vf[i * 2 + 1], pb1, o[i]);
      }
      __builtin_amdgcn_s_setprio(0);
    }

    asm volatile("s_waitcnt vmcnt(0)" ::: "memory");
    __builtin_amdgcn_s_barrier();
    __builtin_amdgcn_sched_barrier(0);
    cur ^= 1;
  }

  float lt = l_r + __shfl_xor(l_r, 16);
  lt += __shfl_xor(lt, 32);
  const float inv = 1.0f / lt;
  bf16_t* yrow = Yg + ((size_t)(b * 2048 + q)) * 1024 + h * 64;
#pragma unroll
  for (int i = 0; i < 4; ++i) {
    bf16x4 yv;
    yv[0] = (bf16_t)(o[i][0] * inv);
    yv[1] = (bf16_t)(o[i][1] * inv);
    yv[2] = (bf16_t)(o[i][2] * inv);
    yv[3] = (bf16_t)(o[i][3] * inv);
    *reinterpret_cast<bf16x4*>(yrow + i * 16 + kb * 4) = yv;
  }
}

// --------------------------------------------------------------- launch ---
extern "C" void kernel_launch(void* const* d_in, const int* in_sizes, int n_in,
                              void* d_out, int out_size, void* d_ws, size_t ws_size,
                              hipStream_t stream) {
  const float* x = (const float*)d_in[0];
  const float* W_attn = (const float*)d_in[1];
  const float* b_attn = (const float*)d_in[2];
  const float* W_proj = (const float*)d_in[3];
  const float* b_proj = (const float*)d_in[4];
  float* out = (float*)d_out;

  char* ws = (char*)d_ws;
  bf16_t* xb  = (bf16_t*)(ws + 0);
  bf16_t* WaT = (bf16_t*)(ws + 16777216);
  bf16_t* WpT = (bf16_t*)(ws + 23068672);
  bf16_t* Qb  = (bf16_t*)(ws + 25165824);
  bf16_t* Kb  = (bf16_t*)(ws + 41943040);
  bf16_t* Vt  = (bf16_t*)(ws + 58720256);
  bf16_t* Yb  = (bf16_t*)(ws + 75497472);

  // fused prep: cvt (8192 blocks) + W_attn transpose (3072) + W_proj (1024)
  prep_fused<<<12288, 256, 0, stream>>>(x, xb, W_attn, WaT, W_proj, WpT);

  // qkv: M=8192, N=3072 -> grid 24x64 = 1536 blocks
  gemm_bf16<0, 1024><<<dim3(24, 64), 256, 0, stream>>>(xb, WaT, b_attn, 8192, 3072,
                                                       Qb, Kb, Vt, nullptr);

  // attention: 1024 blocks x 512 threads (adjacent q-tile pairs)
  attn_fwd<<<1024, 512, 0, stream>>>(Qb, Kb, Vt, Yb);

  // proj: M=8192, N=1024 -> grid 8x64 = 512 blocks
  gemm_bf16<1, 1024><<<dim3(8, 64), 256, 0, stream>>>(Yb, WpT, b_proj, 8192, 1024,
                                                      nullptr, nullptr, nullptr, out);
}